// Round 3
// baseline (568.626 us; speedup 1.0000x reference)
//
#include <hip/hip_runtime.h>

#define B 16
#define H 32
#define KVH 8
#define HD 128
#define S 4096
#define D 4096
#define NQKV 6144   // 4096 q + 1024 k + 1024 v columns
#define PSPLIT 8    // k-split for QKV projection
#define WSPLIT 8    // k-split for Wo projection
#define NCH 16      // chunks per (b,kvh) panel in fused copy kernels
#define CROWS (S / NCH)  // 256 rows per chunk

// ------------------------------------------------- QKV projection (M=16 GEMM)
__global__ void k_proj(const float* __restrict__ hs, const float* __restrict__ Wq,
                       const float* __restrict__ Wk, const float* __restrict__ Wv,
                       float* __restrict__ part) {
  int n = blockIdx.x * 256 + threadIdx.x;
  int k0 = blockIdx.y * (D / PSPLIT);
  const float* w; int ldw, col;
  if (n < 4096)      { w = Wq; ldw = 4096; col = n; }
  else if (n < 5120) { w = Wk; ldw = 1024; col = n - 4096; }
  else               { w = Wv; ldw = 1024; col = n - 5120; }
  float acc[B];
#pragma unroll
  for (int b = 0; b < B; b++) acc[b] = 0.f;
  const float* wp = w + (size_t)k0 * ldw + col;
#pragma unroll 4
  for (int k = 0; k < D / PSPLIT; k++) {
    float wv = wp[(size_t)k * ldw];
#pragma unroll
    for (int b = 0; b < B; b++) acc[b] = fmaf(hs[b * D + k0 + k], wv, acc[b]);
  }
  float* p = part + (size_t)blockIdx.y * (B * NQKV);
#pragma unroll
  for (int b = 0; b < B; b++) p[(size_t)b * NQKV + n] = acc[b];
}

// -------------------------------- reduce partials + RoPE -> qr, new k/v rows
__global__ void k_reduce_rope(const float* __restrict__ part, const float* __restrict__ cosb,
                              const float* __restrict__ sinb, const int* __restrict__ steps,
                              float* __restrict__ qr, float* __restrict__ nkrow,
                              float* __restrict__ nvrow) {
  int i = blockIdx.x * 256 + threadIdx.x;  // < B*NQKV
  int b = i / NQKV, n = i % NQKV;
  float v = 0.f;
#pragma unroll
  for (int c = 0; c < PSPLIT; c++) v += part[(size_t)c * B * NQKV + (size_t)b * NQKV + n];
  if (n < 5120) {
    int d = n & 127;
    int pn = (d < 64) ? n + 64 : n - 64;
    float pv = 0.f;
#pragma unroll
    for (int c = 0; c < PSPLIT; c++) pv += part[(size_t)c * B * NQKV + (size_t)b * NQKV + pn];
    float rot = (d < 64) ? -pv : pv;
    float r = v * cosb[b * HD + d] + rot * sinb[b * HD + d];
    if (n < 4096) qr[(size_t)b * D + n] = r;
    else          nkrow[(size_t)b * KVH * HD + (n - 4096)] = r;
  } else {
    nvrow[(size_t)b * KVH * HD + (n - 5120)] = v;
  }
}

// -------------------- fused: copy past_key -> new_key (+row sub) + QK scores
// Barrier-free: 8-lane group owns one row; lane ln holds float4 slots ln+8i.
__global__ void k_fusedK(const float* __restrict__ pastk, const float* __restrict__ nkrow,
                         const float* __restrict__ qr, const int* __restrict__ steps,
                         float* __restrict__ newk, float* __restrict__ probs) {
  int ch = blockIdx.x, kvh = blockIdx.y, b = blockIdx.z;
  int t = threadIdx.x;
  int rg = t >> 3, ln = t & 7;
  int s0 = ch * CROWS;
  int step = steps[b];
  int h0 = kvh * 4;
  float4 q[4][4];
  const float4* qbase = (const float4*)(qr + ((size_t)b * H + h0) * HD);
#pragma unroll
  for (int h = 0; h < 4; h++)
#pragma unroll
    for (int i = 0; i < 4; i++) q[h][i] = qbase[h * 32 + ln + 8 * i];
  float4 sub[4];
  const float4* subp = (const float4*)(nkrow + (size_t)(b * KVH + kvh) * HD);
#pragma unroll
  for (int i = 0; i < 4; i++) sub[i] = subp[ln + 8 * i];
  const float4* src = (const float4*)(pastk + ((size_t)(b * KVH + kvh) * S + s0) * HD);
  float4*       dst = (float4*)(newk + ((size_t)(b * KVH + kvh) * S + s0) * HD);
  for (int tile = 0; tile < CROWS / 32; ++tile) {
    int row = s0 + tile * 32 + rg;
    size_t base = (size_t)(tile * 32 + rg) * 32 + ln;
    float4 v[4];
#pragma unroll
    for (int i = 0; i < 4; i++) v[i] = src[base + 8 * i];
    bool is_step = (row == step);
#pragma unroll
    for (int i = 0; i < 4; i++) {
      if (is_step) v[i] = sub[i];
      dst[base + 8 * i] = v[i];
    }
    float acc[4];
#pragma unroll
    for (int h = 0; h < 4; h++) {
      float a = 0.f;
#pragma unroll
      for (int i = 0; i < 4; i++)
        a = fmaf(v[i].x, q[h][i].x, fmaf(v[i].y, q[h][i].y,
            fmaf(v[i].z, q[h][i].z, fmaf(v[i].w, q[h][i].w, a))));
      acc[h] = a;
    }
#pragma unroll
    for (int o = 1; o < 8; o <<= 1)
#pragma unroll
      for (int h = 0; h < 4; h++) acc[h] += __shfl_xor(acc[h], o);
    if (ln < 4) {
      float myacc = (ln == 0) ? acc[0] : (ln == 1) ? acc[1] : (ln == 2) ? acc[2] : acc[3];
      probs[(size_t)(b * H + h0 + ln) * S + row] = myacc * 0.08838834764831845f;
    }
  }
}

// ----------------------------------------------- softmax over scores (per b,h)
__global__ void k_softmax(const int* __restrict__ steps, float* __restrict__ probs,
                          float* __restrict__ invs) {
  int bid = blockIdx.x;
  int b = bid >> 5, h = bid & 31;
  int t = threadIdx.x;
  __shared__ float red[4];
  int L = steps[b] + 1;
  float* pb = probs + (size_t)(b * H + h) * S;
  float lmax = -1e30f;
  for (int s = t; s < L; s += 256) lmax = fmaxf(lmax, pb[s]);
#pragma unroll
  for (int o = 32; o > 0; o >>= 1) lmax = fmaxf(lmax, __shfl_xor(lmax, o));
  if ((t & 63) == 0) red[t >> 6] = lmax;
  __syncthreads();
  float gmax = fmaxf(fmaxf(red[0], red[1]), fmaxf(red[2], red[3]));
  float lsum = 0.f;
  for (int s = t; s < L; s += 256) {
    float p = __expf(pb[s] - gmax);
    pb[s] = p;
    lsum += p;
  }
#pragma unroll
  for (int o = 32; o > 0; o >>= 1) lsum += __shfl_xor(lsum, o);
  __syncthreads();
  if ((t & 63) == 0) red[t >> 6] = lsum;
  __syncthreads();
  if (t == 0) invs[b * H + h] = 1.f / (red[0] + red[1] + red[2] + red[3]);
}

// --------------------- fused: copy past_value -> new_value (+row sub) + P·V
// Barrier-free stream; one LDS reduction at block end.
__global__ void k_fusedV(const float* __restrict__ pastv, const float* __restrict__ nvrow,
                         const float* __restrict__ probs, const int* __restrict__ steps,
                         float* __restrict__ newv, float* __restrict__ part) {
  int ch = blockIdx.x, kvh = blockIdx.y, b = blockIdx.z;
  int t = threadIdx.x;
  int rg = t >> 3, ln = t & 7, w = t >> 6;
  int s0 = ch * CROWS;
  int step = steps[b];
  int L = step + 1;
  int h0 = kvh * 4;
  float4 sub[4];
  const float4* subp = (const float4*)(nvrow + (size_t)(b * KVH + kvh) * HD);
#pragma unroll
  for (int i = 0; i < 4; i++) sub[i] = subp[ln + 8 * i];
  float4 acc[4][4];
#pragma unroll
  for (int h = 0; h < 4; h++)
#pragma unroll
    for (int i = 0; i < 4; i++) acc[h][i] = make_float4(0.f, 0.f, 0.f, 0.f);
  const float4* src = (const float4*)(pastv + ((size_t)(b * KVH + kvh) * S + s0) * HD);
  float4*       dst = (float4*)(newv + ((size_t)(b * KVH + kvh) * S + s0) * HD);
  for (int tile = 0; tile < CROWS / 32; ++tile) {
    int row = s0 + tile * 32 + rg;
    size_t base = (size_t)(tile * 32 + rg) * 32 + ln;
    float4 v[4];
#pragma unroll
    for (int i = 0; i < 4; i++) v[i] = src[base + 8 * i];
    bool is_step = (row == step);
#pragma unroll
    for (int i = 0; i < 4; i++) {
      if (is_step) v[i] = sub[i];
      dst[base + 8 * i] = v[i];
    }
    bool act = (row < L);
    float p[4];
#pragma unroll
    for (int h = 0; h < 4; h++)
      p[h] = act ? probs[(size_t)(b * H + h0 + h) * S + row] : 0.f;
#pragma unroll
    for (int h = 0; h < 4; h++)
#pragma unroll
      for (int i = 0; i < 4; i++) {
        acc[h][i].x = fmaf(p[h], v[i].x, acc[h][i].x);
        acc[h][i].y = fmaf(p[h], v[i].y, acc[h][i].y);
        acc[h][i].z = fmaf(p[h], v[i].z, acc[h][i].z);
        acc[h][i].w = fmaf(p[h], v[i].w, acc[h][i].w);
      }
  }
  // reduce over the 8 row-groups within each wave (lanes differing in bits 3..5)
#pragma unroll
  for (int o = 8; o < 64; o <<= 1)
#pragma unroll
    for (int h = 0; h < 4; h++)
#pragma unroll
      for (int i = 0; i < 4; i++) {
        acc[h][i].x += __shfl_xor(acc[h][i].x, o);
        acc[h][i].y += __shfl_xor(acc[h][i].y, o);
        acc[h][i].z += __shfl_xor(acc[h][i].z, o);
        acc[h][i].w += __shfl_xor(acc[h][i].w, o);
      }
  __shared__ float4 red[4][4][32];  // [wave][h][d4]
  if ((rg & 7) == 0) {
#pragma unroll
    for (int h = 0; h < 4; h++)
#pragma unroll
      for (int i = 0; i < 4; i++) red[w][h][ln + 8 * i] = acc[h][i];
  }
  __syncthreads();
  if (t < 128) {
    int h = t >> 5, d4 = t & 31;
    float4 a = red[0][h][d4], b4 = red[1][h][d4], c = red[2][h][d4], d = red[3][h][d4];
    float4 s;
    s.x = a.x + b4.x + c.x + d.x;
    s.y = a.y + b4.y + c.y + d.y;
    s.z = a.z + b4.z + c.z + d.z;
    s.w = a.w + b4.w + c.w + d.w;
    float4* o = (float4*)(part + (((size_t)ch * B + b) * KVH + kvh) * 512) + h * 32 + d4;
    *o = s;
  }
}

__global__ void k_reduce_ctx(const float* __restrict__ part, const float* __restrict__ invs,
                             float* __restrict__ ctx) {
  int i = blockIdx.x * 256 + threadIdx.x;  // < B*D
  int b = i >> 12, r = i & 4095, h = r >> 7, d = r & 127;
  int kvh = h >> 2, hl = h & 3;
  float s = 0.f;
#pragma unroll
  for (int c = 0; c < NCH; c++)
    s += part[(((size_t)c * B + b) * KVH + kvh) * 512 + hl * 128 + d];
  ctx[i] = s * invs[b * H + h];
}

// ----------------------------------------------- output projection (M=16)
__global__ void k_wo(const float* __restrict__ ctx, const float* __restrict__ Wo,
                     float* __restrict__ part) {
  int n = blockIdx.x * 256 + threadIdx.x;  // < 4096
  int k0 = blockIdx.y * (D / WSPLIT);
  float acc[B];
#pragma unroll
  for (int b = 0; b < B; b++) acc[b] = 0.f;
  const float* wp = Wo + (size_t)k0 * D + n;
#pragma unroll 4
  for (int k = 0; k < D / WSPLIT; k++) {
    float wv = wp[(size_t)k * D];
#pragma unroll
    for (int b = 0; b < B; b++) acc[b] = fmaf(ctx[b * D + k0 + k], wv, acc[b]);
  }
  float* p = part + (size_t)blockIdx.y * (B * D);
#pragma unroll
  for (int b = 0; b < B; b++) p[(size_t)b * D + n] = acc[b];
}

__global__ void k_reduce_out(const float* __restrict__ part, float* __restrict__ out) {
  int i = blockIdx.x * 256 + threadIdx.x;  // < B*D
  float s = 0.f;
#pragma unroll
  for (int c = 0; c < WSPLIT; c++) s += part[(size_t)c * B * D + i];
  out[i] = s;
}

// ----------------------------------------------------------------- launch
extern "C" void kernel_launch(void* const* d_in, const int* in_sizes, int n_in,
                              void* d_out, int out_size, void* d_ws, size_t ws_size,
                              hipStream_t stream) {
  const float* hs    = (const float*)d_in[0];
  const int*   steps = (const int*)d_in[2];
  const float* cosb  = (const float*)d_in[3];
  const float* sinb  = (const float*)d_in[4];
  const float* pk    = (const float*)d_in[5];
  const float* pvv   = (const float*)d_in[6];
  const float* Wq    = (const float*)d_in[7];
  const float* Wk    = (const float*)d_in[8];
  const float* Wv    = (const float*)d_in[9];
  const float* Wo    = (const float*)d_in[10];

  float* attn_out = (float*)d_out;
  float* newk = attn_out + (size_t)B * D;
  float* newv = newk + (size_t)B * KVH * S * HD;

  float* ws = (float*)d_ws;
  float* p_shared = ws;                                        // 1,048,576 floats
  float* p_qr     = p_shared + 1048576;                        //    65,536
  float* p_nkrow  = p_qr + (size_t)B * D;                      //    16,384
  float* p_nvrow  = p_nkrow + (size_t)B * KVH * HD;            //    16,384
  float* p_probs  = p_nvrow + (size_t)B * KVH * HD;            // 2,097,152
  float* p_invs   = p_probs + (size_t)B * H * S;               //       512
  float* p_ctx    = p_invs + 512;                              //    65,536

  hipLaunchKernelGGL(k_proj, dim3(NQKV / 256, PSPLIT), dim3(256), 0, stream,
                     hs, Wq, Wk, Wv, p_shared);
  hipLaunchKernelGGL(k_reduce_rope, dim3(B * NQKV / 256), dim3(256), 0, stream,
                     p_shared, cosb, sinb, steps, p_qr, p_nkrow, p_nvrow);
  hipLaunchKernelGGL(k_fusedK, dim3(NCH, KVH, B), dim3(256), 0, stream,
                     pk, p_nkrow, p_qr, steps, newk, p_probs);
  hipLaunchKernelGGL(k_softmax, dim3(B * H), dim3(256), 0, stream,
                     steps, p_probs, p_invs);
  hipLaunchKernelGGL(k_fusedV, dim3(NCH, KVH, B), dim3(256), 0, stream,
                     pvv, p_nvrow, p_probs, steps, newv, p_shared);
  hipLaunchKernelGGL(k_reduce_ctx, dim3(B * D / 256), dim3(256), 0, stream,
                     p_shared, p_invs, p_ctx);
  hipLaunchKernelGGL(k_wo, dim3(D / 256, WSPLIT), dim3(256), 0, stream,
                     p_ctx, Wo, p_shared);
  hipLaunchKernelGGL(k_reduce_out, dim3(B * D / 256), dim3(256), 0, stream,
                     p_shared, attn_out);
}

// Round 4
// 386.816 us; speedup vs baseline: 1.4700x; 1.4700x over previous
//
#include <hip/hip_runtime.h>

#define B 16
#define H 32
#define KVH 8
#define HD 128
#define S 4096
#define D 4096
#define NQKV 6144   // 4096 q + 1024 k + 1024 v columns
#define PSPLIT 16   // k-split for QKV projection
#define WSPLIT 16   // k-split for Wo projection
#define NCH 16      // chunks per (b,kvh) panel in fused copy kernels
#define CROWS (S / NCH)  // 256 rows per chunk
#define SCALE 0.08838834764831845f  // 1/sqrt(128)

// ------------------------------------------------- QKV projection (M=16 GEMM)
__global__ void k_proj(const float* __restrict__ hs, const float* __restrict__ Wq,
                       const float* __restrict__ Wk, const float* __restrict__ Wv,
                       float* __restrict__ part) {
  int n = blockIdx.x * 256 + threadIdx.x;
  int k0 = blockIdx.y * (D / PSPLIT);
  const float* w; int ldw, col;
  if (n < 4096)      { w = Wq; ldw = 4096; col = n; }
  else if (n < 5120) { w = Wk; ldw = 1024; col = n - 4096; }
  else               { w = Wv; ldw = 1024; col = n - 5120; }
  float acc[B];
#pragma unroll
  for (int b = 0; b < B; b++) acc[b] = 0.f;
  const float* wp = w + (size_t)k0 * ldw + col;
#pragma unroll 8
  for (int k = 0; k < D / PSPLIT; k++) {
    float wv = wp[(size_t)k * ldw];
#pragma unroll
    for (int b = 0; b < B; b++) acc[b] = fmaf(hs[b * D + k0 + k], wv, acc[b]);
  }
  float* p = part + (size_t)blockIdx.y * (B * NQKV);
#pragma unroll
  for (int b = 0; b < B; b++) p[(size_t)b * NQKV + n] = acc[b];
}

// -------------------------------- reduce partials + RoPE -> qr, new k/v rows
__global__ void k_reduce_rope(const float* __restrict__ part, const float* __restrict__ cosb,
                              const float* __restrict__ sinb, const int* __restrict__ steps,
                              float* __restrict__ qr, float* __restrict__ nkrow,
                              float* __restrict__ nvrow) {
  int i = blockIdx.x * 256 + threadIdx.x;  // < B*NQKV
  int b = i / NQKV, n = i % NQKV;
  float v = 0.f;
#pragma unroll
  for (int c = 0; c < PSPLIT; c++) v += part[(size_t)c * B * NQKV + (size_t)b * NQKV + n];
  if (n < 5120) {
    int d = n & 127;
    int pn = (d < 64) ? n + 64 : n - 64;
    float pv = 0.f;
#pragma unroll
    for (int c = 0; c < PSPLIT; c++) pv += part[(size_t)c * B * NQKV + (size_t)b * NQKV + pn];
    float rot = (d < 64) ? -pv : pv;
    float r = v * cosb[b * HD + d] + rot * sinb[b * HD + d];
    if (n < 4096) qr[(size_t)b * D + n] = r;
    else          nkrow[(size_t)b * KVH * HD + (n - 4096)] = r;
  } else {
    nvrow[(size_t)b * KVH * HD + (n - 5120)] = v;
  }
}

// -------------------- fused: copy past_key -> new_key (+row sub) + QK scores
// LDS staging, XOR-swizzled (slot = d4 ^ (row&7)), all-256-thread score compute.
__global__ void k_fusedK(const float* __restrict__ pastk, const float* __restrict__ nkrow,
                         const float* __restrict__ qr, const int* __restrict__ steps,
                         float* __restrict__ newk, float* __restrict__ scores) {
  int ch = blockIdx.x, kvh = blockIdx.y, b = blockIdx.z;
  int t = threadIdx.x;
  __shared__ float4 qs4[128];      // 4 heads x 32 float4
  __shared__ float4 ks4[32 * 32];  // 32 rows x 32 float4, swizzled
  int s0 = ch * CROWS;
  int step = steps[b];
  int L = step + 1;
  int h0 = kvh * 4;
  if (t < 128) qs4[t] = ((const float4*)(qr + ((size_t)b * H + h0) * HD))[t];
  float4 subv = ((const float4*)(nkrow + (size_t)(b * KVH + kvh) * HD))[t & 31];
  const float4* src = (const float4*)(pastk + ((size_t)(b * KVH + kvh) * S + s0) * HD);
  float4*       dst = (float4*)(newk + ((size_t)(b * KVH + kvh) * S + s0) * HD);
  int row_c = t & 31, half = (t >> 5) & 1, h = t >> 6;
  float* srow = scores + (size_t)(b * H + h0 + h) * S + s0;
  int d4 = t & 31, r0 = t >> 5;
  __syncthreads();
  for (int tile = 0; tile < CROWS / 32; ++tile) {
    int rbase = s0 + tile * 32;
    float4 v0 = src[tile * 1024 + t];
    float4 v1 = src[tile * 1024 + 256 + t];
    float4 v2 = src[tile * 1024 + 512 + t];
    float4 v3 = src[tile * 1024 + 768 + t];
    if (rbase + r0      == step) v0 = subv;
    if (rbase + r0 + 8  == step) v1 = subv;
    if (rbase + r0 + 16 == step) v2 = subv;
    if (rbase + r0 + 24 == step) v3 = subv;
    dst[tile * 1024 + t] = v0;
    dst[tile * 1024 + 256 + t] = v1;
    dst[tile * 1024 + 512 + t] = v2;
    dst[tile * 1024 + 768 + t] = v3;
    ks4[r0 * 32        + (d4 ^ (r0 & 7))]        = v0;
    ks4[(r0 + 8) * 32  + (d4 ^ ((r0 + 8) & 7))]  = v1;
    ks4[(r0 + 16) * 32 + (d4 ^ ((r0 + 16) & 7))] = v2;
    ks4[(r0 + 24) * 32 + (d4 ^ ((r0 + 24) & 7))] = v3;
    __syncthreads();
    if (rbase < L) {
      float a0 = 0.f, a1 = 0.f, a2 = 0.f, a3 = 0.f;
      const float4* qp = &qs4[h * 32 + half * 16];
      const float4* kp = &ks4[row_c * 32];
      int sw = row_c & 7;
#pragma unroll
      for (int r = 0; r < 16; r += 4) {
        float4 k0v = kp[(half * 16 + r)     ^ sw], q0v = qp[r];
        float4 k1v = kp[(half * 16 + r + 1) ^ sw], q1v = qp[r + 1];
        float4 k2v = kp[(half * 16 + r + 2) ^ sw], q2v = qp[r + 2];
        float4 k3v = kp[(half * 16 + r + 3) ^ sw], q3v = qp[r + 3];
        a0 = fmaf(k0v.x, q0v.x, fmaf(k0v.y, q0v.y, fmaf(k0v.z, q0v.z, fmaf(k0v.w, q0v.w, a0))));
        a1 = fmaf(k1v.x, q1v.x, fmaf(k1v.y, q1v.y, fmaf(k1v.z, q1v.z, fmaf(k1v.w, q1v.w, a1))));
        a2 = fmaf(k2v.x, q2v.x, fmaf(k2v.y, q2v.y, fmaf(k2v.z, q2v.z, fmaf(k2v.w, q2v.w, a2))));
        a3 = fmaf(k3v.x, q3v.x, fmaf(k3v.y, q3v.y, fmaf(k3v.z, q3v.z, fmaf(k3v.w, q3v.w, a3))));
      }
      float accv = (a0 + a1) + (a2 + a3);
      accv += __shfl_xor(accv, 32);
      if (half == 0) srow[tile * 32 + row_c] = accv * SCALE;
    }
    __syncthreads();
  }
}

// ------------------------------- softmax stats only: gmax + 1/sum per (b,h)
__global__ void k_smax(const float* __restrict__ scores, const int* __restrict__ steps,
                       float* __restrict__ gmax, float* __restrict__ inv) {
  int bid = blockIdx.x;
  int b = bid >> 5, h = bid & 31;
  int t = threadIdx.x;
  __shared__ float red[4];
  int L = steps[b] + 1;
  const float* srow = scores + (size_t)(b * H + h) * S;
  float lmax = -1e30f;
  for (int s = t; s < L; s += 256) lmax = fmaxf(lmax, srow[s]);
#pragma unroll
  for (int o = 32; o > 0; o >>= 1) lmax = fmaxf(lmax, __shfl_xor(lmax, o));
  if ((t & 63) == 0) red[t >> 6] = lmax;
  __syncthreads();
  float gm = fmaxf(fmaxf(red[0], red[1]), fmaxf(red[2], red[3]));
  float lsum = 0.f;
  for (int s = t; s < L; s += 256) lsum += __expf(srow[s] - gm);
#pragma unroll
  for (int o = 32; o > 0; o >>= 1) lsum += __shfl_xor(lsum, o);
  __syncthreads();
  if ((t & 63) == 0) red[t >> 6] = lsum;
  __syncthreads();
  if (t == 0) {
    gmax[bid] = gm;
    inv[bid] = 1.f / (red[0] + red[1] + red[2] + red[3]);
  }
}

// --------------------- fused: copy past_value -> new_value (+row sub) + P·V
// exp(s-gmax) on the fly; one wave per head; register accumulation.
__global__ void k_fusedV(const float* __restrict__ pastv, const float* __restrict__ nvrow,
                         const float* __restrict__ scores, const float* __restrict__ gmax,
                         const int* __restrict__ steps,
                         float* __restrict__ newv, float* __restrict__ part) {
  int ch = blockIdx.x, kvh = blockIdx.y, b = blockIdx.z;
  int t = threadIdx.x;
  __shared__ float4 vs4[32 * 32];  // swizzled
  __shared__ float ps[4 * 32];
  int s0 = ch * CROWS;
  int step = steps[b];
  int L = step + 1;
  int h0 = kvh * 4;
  float4 subv = ((const float4*)(nvrow + (size_t)(b * KVH + kvh) * HD))[t & 31];
  const float4* src = (const float4*)(pastv + ((size_t)(b * KVH + kvh) * S + s0) * HD);
  float4*       dst = (float4*)(newv + ((size_t)(b * KVH + kvh) * S + s0) * HD);
  int h = t >> 6, dl = t & 63;
  float gm = gmax[b * H + h0 + ((t >> 5) & 3)];
  float2 acc = make_float2(0.f, 0.f);
  const float2* vs2 = (const float2*)vs4;
  int d4 = t & 31, r0 = t >> 5;
  for (int tile = 0; tile < CROWS / 32; ++tile) {
    int rbase = s0 + tile * 32;
    float4 v0 = src[tile * 1024 + t];
    float4 v1 = src[tile * 1024 + 256 + t];
    float4 v2 = src[tile * 1024 + 512 + t];
    float4 v3 = src[tile * 1024 + 768 + t];
    if (rbase + r0      == step) v0 = subv;
    if (rbase + r0 + 8  == step) v1 = subv;
    if (rbase + r0 + 16 == step) v2 = subv;
    if (rbase + r0 + 24 == step) v3 = subv;
    dst[tile * 1024 + t] = v0;
    dst[tile * 1024 + 256 + t] = v1;
    dst[tile * 1024 + 512 + t] = v2;
    dst[tile * 1024 + 768 + t] = v3;
    vs4[r0 * 32        + (d4 ^ (r0 & 7))]        = v0;
    vs4[(r0 + 8) * 32  + (d4 ^ ((r0 + 8) & 7))]  = v1;
    vs4[(r0 + 16) * 32 + (d4 ^ ((r0 + 16) & 7))] = v2;
    vs4[(r0 + 24) * 32 + (d4 ^ ((r0 + 24) & 7))] = v3;
    if (t < 128 && rbase < L) {
      int h2 = t >> 5, row = t & 31;
      float sc = scores[(size_t)(b * H + h0 + h2) * S + rbase + row];
      ps[h2 * 32 + row] = (rbase + row < L) ? __expf(sc - gm) : 0.f;
    }
    __syncthreads();
    if (rbase < L) {
#pragma unroll
      for (int row = 0; row < 32; ++row) {
        float p = ps[h * 32 + row];
        float2 vv = vs2[row * 64 + ((dl >> 1) ^ (row & 7)) * 2 + (dl & 1)];
        acc.x = fmaf(p, vv.x, acc.x);
        acc.y = fmaf(p, vv.y, acc.y);
      }
    }
    __syncthreads();
  }
  float2* o = (float2*)(part + (((size_t)ch * B + b) * KVH + kvh) * 512) + t;
  *o = acc;
}

__global__ void k_reduce_ctx(const float* __restrict__ part, const float* __restrict__ inv,
                             float* __restrict__ ctx) {
  int i = blockIdx.x * 256 + threadIdx.x;  // < B*D
  int b = i >> 12, r = i & 4095, h = r >> 7, d = r & 127;
  int kvh = h >> 2, hl = h & 3;
  float s = 0.f;
#pragma unroll
  for (int c = 0; c < NCH; c++)
    s += part[(((size_t)c * B + b) * KVH + kvh) * 512 + hl * 128 + d];
  ctx[i] = s * inv[b * H + h];
}

// ----------------------------------------------- output projection (M=16)
__global__ void k_wo(const float* __restrict__ ctx, const float* __restrict__ Wo,
                     float* __restrict__ part) {
  int n = blockIdx.x * 256 + threadIdx.x;  // < 4096
  int k0 = blockIdx.y * (D / WSPLIT);
  float acc[B];
#pragma unroll
  for (int b = 0; b < B; b++) acc[b] = 0.f;
  const float* wp = Wo + (size_t)k0 * D + n;
#pragma unroll 8
  for (int k = 0; k < D / WSPLIT; k++) {
    float wv = wp[(size_t)k * D];
#pragma unroll
    for (int b = 0; b < B; b++) acc[b] = fmaf(ctx[b * D + k0 + k], wv, acc[b]);
  }
  float* p = part + (size_t)blockIdx.y * (B * D);
#pragma unroll
  for (int b = 0; b < B; b++) p[(size_t)b * D + n] = acc[b];
}

__global__ void k_reduce_out(const float* __restrict__ part, float* __restrict__ out) {
  int i = blockIdx.x * 256 + threadIdx.x;  // < B*D
  float s = 0.f;
#pragma unroll
  for (int c = 0; c < WSPLIT; c++) s += part[(size_t)c * B * D + i];
  out[i] = s;
}

// ----------------------------------------------------------------- launch
extern "C" void kernel_launch(void* const* d_in, const int* in_sizes, int n_in,
                              void* d_out, int out_size, void* d_ws, size_t ws_size,
                              hipStream_t stream) {
  const float* hs    = (const float*)d_in[0];
  const int*   steps = (const int*)d_in[2];
  const float* cosb  = (const float*)d_in[3];
  const float* sinb  = (const float*)d_in[4];
  const float* pk    = (const float*)d_in[5];
  const float* pvv   = (const float*)d_in[6];
  const float* Wq    = (const float*)d_in[7];
  const float* Wk    = (const float*)d_in[8];
  const float* Wv    = (const float*)d_in[9];
  const float* Wo    = (const float*)d_in[10];

  float* attn_out = (float*)d_out;
  float* newk = attn_out + (size_t)B * D;
  float* newv = newk + (size_t)B * KVH * S * HD;

  float* ws = (float*)d_ws;
  // p_part: proj partials (16*16*6144 = 1,572,864) -> reused for PV partials (1,048,576)
  float* p_part   = ws;
  float* p_qr     = p_part + 1572864;                 //    65,536
  float* p_nkrow  = p_qr + (size_t)B * D;             //    16,384
  float* p_nvrow  = p_nkrow + (size_t)B * KVH * HD;   //    16,384
  // p_scores: 2,097,152 -> reused for Wo partials (1,048,576)
  float* p_scores = p_nvrow + (size_t)B * KVH * HD;
  float* p_gmax   = p_scores + (size_t)B * H * S;     //       512
  float* p_inv    = p_gmax + 512;                     //       512
  float* p_ctx    = p_inv + 512;                      //    65,536

  hipLaunchKernelGGL(k_proj, dim3(NQKV / 256, PSPLIT), dim3(256), 0, stream,
                     hs, Wq, Wk, Wv, p_part);
  hipLaunchKernelGGL(k_reduce_rope, dim3(B * NQKV / 256), dim3(256), 0, stream,
                     p_part, cosb, sinb, steps, p_qr, p_nkrow, p_nvrow);
  hipLaunchKernelGGL(k_fusedK, dim3(NCH, KVH, B), dim3(256), 0, stream,
                     pk, p_nkrow, p_qr, steps, newk, p_scores);
  hipLaunchKernelGGL(k_smax, dim3(B * H), dim3(256), 0, stream,
                     p_scores, steps, p_gmax, p_inv);
  hipLaunchKernelGGL(k_fusedV, dim3(NCH, KVH, B), dim3(256), 0, stream,
                     pvv, p_nvrow, p_scores, p_gmax, steps, newv, p_part);
  hipLaunchKernelGGL(k_reduce_ctx, dim3(B * D / 256), dim3(256), 0, stream,
                     p_part, p_inv, p_ctx);
  hipLaunchKernelGGL(k_wo, dim3(D / 256, WSPLIT), dim3(256), 0, stream,
                     p_ctx, Wo, p_scores);
  hipLaunchKernelGGL(k_reduce_out, dim3(B * D / 256), dim3(256), 0, stream,
                     p_scores, attn_out);
}

// Round 5
// 335.738 us; speedup vs baseline: 1.6937x; 1.1521x over previous
//
#include <hip/hip_runtime.h>

#define B 16
#define H 32
#define KVH 8
#define HD 128
#define S 4096
#define D 4096
#define NQKV 6144   // 4096 q + 1024 k + 1024 v columns
#define PSPLIT 32   // k-split for QKV projection
#define WSPLIT 32   // k-split for Wo projection
#define NCH 16      // chunks per (b,kvh) panel in fused copy kernels
#define CROWS (S / NCH)  // 256 rows per chunk
#define SCALE 0.08838834764831845f  // 1/sqrt(128)

// ------------------------------------------------- QKV projection (M=16 GEMM)
__global__ void k_proj(const float* __restrict__ hs, const float* __restrict__ Wq,
                       const float* __restrict__ Wk, const float* __restrict__ Wv,
                       float* __restrict__ part) {
  int n = blockIdx.x * 256 + threadIdx.x;
  int k0 = blockIdx.y * (D / PSPLIT);
  const float* w; int ldw, col;
  if (n < 4096)      { w = Wq; ldw = 4096; col = n; }
  else if (n < 5120) { w = Wk; ldw = 1024; col = n - 4096; }
  else               { w = Wv; ldw = 1024; col = n - 5120; }
  float acc[B];
#pragma unroll
  for (int b = 0; b < B; b++) acc[b] = 0.f;
  const float* wp = w + (size_t)k0 * ldw + col;
#pragma unroll 8
  for (int k = 0; k < D / PSPLIT; k++) {
    float wv = wp[(size_t)k * ldw];
#pragma unroll
    for (int b = 0; b < B; b++) acc[b] = fmaf(hs[b * D + k0 + k], wv, acc[b]);
  }
  float* p = part + (size_t)blockIdx.y * (B * NQKV);
#pragma unroll
  for (int b = 0; b < B; b++) p[(size_t)b * NQKV + n] = acc[b];
}

// -------------------------------- reduce partials + RoPE -> qr, new k/v rows
__global__ void k_reduce_rope(const float* __restrict__ part, const float* __restrict__ cosb,
                              const float* __restrict__ sinb, const int* __restrict__ steps,
                              float* __restrict__ qr, float* __restrict__ nkrow,
                              float* __restrict__ nvrow) {
  int i = blockIdx.x * 256 + threadIdx.x;  // < B*NQKV
  int b = i / NQKV, n = i % NQKV;
  float v = 0.f;
#pragma unroll
  for (int c = 0; c < PSPLIT; c++) v += part[(size_t)c * B * NQKV + (size_t)b * NQKV + n];
  if (n < 5120) {
    int d = n & 127;
    int pn = (d < 64) ? n + 64 : n - 64;
    float pv = 0.f;
#pragma unroll
    for (int c = 0; c < PSPLIT; c++) pv += part[(size_t)c * B * NQKV + (size_t)b * NQKV + pn];
    float rot = (d < 64) ? -pv : pv;
    float r = v * cosb[b * HD + d] + rot * sinb[b * HD + d];
    if (n < 4096) qr[(size_t)b * D + n] = r;
    else          nkrow[(size_t)b * KVH * HD + (n - 4096)] = r;
  } else {
    nvrow[(size_t)b * KVH * HD + (n - 5120)] = v;
  }
}

// -------------------- fused: copy past_key -> new_key (+row sub) + QK scores
// LDS staging with XOR swizzle + register prefetch of the next tile so global
// loads stay in flight across the compute barriers.
__global__ void k_fusedK(const float* __restrict__ pastk, const float* __restrict__ nkrow,
                         const float* __restrict__ qr, const int* __restrict__ steps,
                         float* __restrict__ newk, float* __restrict__ scores) {
  int ch = blockIdx.x, kvh = blockIdx.y, b = blockIdx.z;
  int t = threadIdx.x;
  __shared__ float4 qs4[128];      // 4 heads x 32 float4
  __shared__ float4 ks4[32 * 32];  // 32 rows x 32 float4, swizzled
  int s0 = ch * CROWS;
  int step = steps[b];
  int L = step + 1;
  int h0 = kvh * 4;
  if (t < 128) qs4[t] = ((const float4*)(qr + ((size_t)b * H + h0) * HD))[t];
  float4 subv = ((const float4*)(nkrow + (size_t)(b * KVH + kvh) * HD))[t & 31];
  const float4* src = (const float4*)(pastk + ((size_t)(b * KVH + kvh) * S + s0) * HD);
  float4*       dst = (float4*)(newk + ((size_t)(b * KVH + kvh) * S + s0) * HD);
  int row_c = t & 31, half = (t >> 5) & 1, h = t >> 6;
  float* srow = scores + (size_t)(b * H + h0 + h) * S + s0;
  int d4 = t & 31, r0 = t >> 5;
  // prologue: load tile 0 into regs
  float4 v0 = src[t];
  float4 v1 = src[256 + t];
  float4 v2 = src[512 + t];
  float4 v3 = src[768 + t];
  __syncthreads();
  for (int tile = 0; tile < CROWS / 32; ++tile) {
    int rbase = s0 + tile * 32;
    if (rbase + r0      == step) v0 = subv;
    if (rbase + r0 + 8  == step) v1 = subv;
    if (rbase + r0 + 16 == step) v2 = subv;
    if (rbase + r0 + 24 == step) v3 = subv;
    dst[tile * 1024 + t] = v0;
    dst[tile * 1024 + 256 + t] = v1;
    dst[tile * 1024 + 512 + t] = v2;
    dst[tile * 1024 + 768 + t] = v3;
    ks4[r0 * 32        + (d4 ^ (r0 & 7))]        = v0;
    ks4[(r0 + 8) * 32  + (d4 ^ ((r0 + 8) & 7))]  = v1;
    ks4[(r0 + 16) * 32 + (d4 ^ ((r0 + 16) & 7))] = v2;
    ks4[(r0 + 24) * 32 + (d4 ^ ((r0 + 24) & 7))] = v3;
    // prefetch next tile (stays in flight through both barriers + compute)
    float4 n0, n1, n2, n3;
    bool more = (tile + 1 < CROWS / 32);
    if (more) {
      n0 = src[(tile + 1) * 1024 + t];
      n1 = src[(tile + 1) * 1024 + 256 + t];
      n2 = src[(tile + 1) * 1024 + 512 + t];
      n3 = src[(tile + 1) * 1024 + 768 + t];
    }
    __syncthreads();
    if (rbase < L) {
      float a0 = 0.f, a1 = 0.f, a2 = 0.f, a3 = 0.f;
      const float4* qp = &qs4[h * 32 + half * 16];
      const float4* kp = &ks4[row_c * 32];
      int sw = row_c & 7;
#pragma unroll
      for (int r = 0; r < 16; r += 4) {
        float4 k0v = kp[(half * 16 + r)     ^ sw], q0v = qp[r];
        float4 k1v = kp[(half * 16 + r + 1) ^ sw], q1v = qp[r + 1];
        float4 k2v = kp[(half * 16 + r + 2) ^ sw], q2v = qp[r + 2];
        float4 k3v = kp[(half * 16 + r + 3) ^ sw], q3v = qp[r + 3];
        a0 = fmaf(k0v.x, q0v.x, fmaf(k0v.y, q0v.y, fmaf(k0v.z, q0v.z, fmaf(k0v.w, q0v.w, a0))));
        a1 = fmaf(k1v.x, q1v.x, fmaf(k1v.y, q1v.y, fmaf(k1v.z, q1v.z, fmaf(k1v.w, q1v.w, a1))));
        a2 = fmaf(k2v.x, q2v.x, fmaf(k2v.y, q2v.y, fmaf(k2v.z, q2v.z, fmaf(k2v.w, q2v.w, a2))));
        a3 = fmaf(k3v.x, q3v.x, fmaf(k3v.y, q3v.y, fmaf(k3v.z, q3v.z, fmaf(k3v.w, q3v.w, a3))));
      }
      float accv = (a0 + a1) + (a2 + a3);
      accv += __shfl_xor(accv, 32);
      if (half == 0) srow[tile * 32 + row_c] = accv * SCALE;
    }
    __syncthreads();
    if (more) { v0 = n0; v1 = n1; v2 = n2; v3 = n3; }
  }
}

// --------------- softmax: in-place normalize scores -> probs (per b,h)
__global__ void k_smax(float* __restrict__ scores, const int* __restrict__ steps) {
  int bid = blockIdx.x;
  int b = bid >> 5, h = bid & 31;
  int t = threadIdx.x;
  __shared__ float red[4];
  int L = steps[b] + 1;
  float* srow = scores + (size_t)(b * H + h) * S;
  float lmax = -1e30f;
  for (int s = t; s < L; s += 256) lmax = fmaxf(lmax, srow[s]);
#pragma unroll
  for (int o = 32; o > 0; o >>= 1) lmax = fmaxf(lmax, __shfl_xor(lmax, o));
  if ((t & 63) == 0) red[t >> 6] = lmax;
  __syncthreads();
  float gm = fmaxf(fmaxf(red[0], red[1]), fmaxf(red[2], red[3]));
  float lsum = 0.f;
  for (int s = t; s < L; s += 256) {
    float p = __expf(srow[s] - gm);
    srow[s] = p;
    lsum += p;
  }
#pragma unroll
  for (int o = 32; o > 0; o >>= 1) lsum += __shfl_xor(lsum, o);
  __syncthreads();
  if ((t & 63) == 0) red[t >> 6] = lsum;
  __syncthreads();
  float inv = 1.f / (red[0] + red[1] + red[2] + red[3]);
  for (int s = t; s < L; s += 256) srow[s] *= inv;
}

// --------------- fused: copy past_value -> new_value (+row sub) + P·V
// Barrier-free stream: lane owns (d4, row-slice); probs are pre-normalized,
// read as row-uniform broadcast loads. Single LDS reduce at block end.
__global__ void k_fusedV(const float* __restrict__ pastv, const float* __restrict__ nvrow,
                         const float* __restrict__ probs, const int* __restrict__ steps,
                         float* __restrict__ newv, float* __restrict__ part) {
  int ch = blockIdx.x, kvh = blockIdx.y, b = blockIdx.z;
  int t = threadIdx.x;
  int d4 = t & 31, rr = t >> 5;  // rr in 0..7
  int s0 = ch * CROWS;
  int step = steps[b];
  int L = step + 1;
  int h0 = kvh * 4;
  float4 subv = ((const float4*)(nvrow + (size_t)(b * KVH + kvh) * HD))[d4];
  const float4* src = (const float4*)(pastv + ((size_t)(b * KVH + kvh) * S + s0) * HD);
  float4*       dst = (float4*)(newv + ((size_t)(b * KVH + kvh) * S + s0) * HD);
  const float* pb = probs + (size_t)(b * H + h0) * S + s0;
  float4 a0 = make_float4(0.f, 0.f, 0.f, 0.f), a1 = a0, a2 = a0, a3 = a0;
#pragma unroll 4
  for (int i = 0; i < CROWS / 8; ++i) {
    int r = i * 8 + rr;
    float4 v = src[r * 32 + d4];
    if (s0 + r == step) v = subv;
    dst[r * 32 + d4] = v;
    if (s0 + r < L) {
      float q0 = pb[r], q1 = pb[S + r], q2 = pb[2 * S + r], q3 = pb[3 * S + r];
      a0.x = fmaf(q0, v.x, a0.x); a0.y = fmaf(q0, v.y, a0.y);
      a0.z = fmaf(q0, v.z, a0.z); a0.w = fmaf(q0, v.w, a0.w);
      a1.x = fmaf(q1, v.x, a1.x); a1.y = fmaf(q1, v.y, a1.y);
      a1.z = fmaf(q1, v.z, a1.z); a1.w = fmaf(q1, v.w, a1.w);
      a2.x = fmaf(q2, v.x, a2.x); a2.y = fmaf(q2, v.y, a2.y);
      a2.z = fmaf(q2, v.z, a2.z); a2.w = fmaf(q2, v.w, a2.w);
      a3.x = fmaf(q3, v.x, a3.x); a3.y = fmaf(q3, v.y, a3.y);
      a3.z = fmaf(q3, v.z, a3.z); a3.w = fmaf(q3, v.w, a3.w);
    }
  }
  // combine rr pairs within wave (t^32 flips rr bit 0)
#pragma unroll
  for (int c = 0; c < 1; c++) {
    a0.x += __shfl_xor(a0.x, 32); a0.y += __shfl_xor(a0.y, 32);
    a0.z += __shfl_xor(a0.z, 32); a0.w += __shfl_xor(a0.w, 32);
    a1.x += __shfl_xor(a1.x, 32); a1.y += __shfl_xor(a1.y, 32);
    a1.z += __shfl_xor(a1.z, 32); a1.w += __shfl_xor(a1.w, 32);
    a2.x += __shfl_xor(a2.x, 32); a2.y += __shfl_xor(a2.y, 32);
    a2.z += __shfl_xor(a2.z, 32); a2.w += __shfl_xor(a2.w, 32);
    a3.x += __shfl_xor(a3.x, 32); a3.y += __shfl_xor(a3.y, 32);
    a3.z += __shfl_xor(a3.z, 32); a3.w += __shfl_xor(a3.w, 32);
  }
  __shared__ float4 red[4][4][32];  // [wave][head][d4]
  int w = t >> 6;
  if ((t & 32) == 0) {
    red[w][0][d4] = a0; red[w][1][d4] = a1; red[w][2][d4] = a2; red[w][3][d4] = a3;
  }
  __syncthreads();
  if (t < 128) {
    int hh = t >> 5, dd = t & 31;
    float4 x0 = red[0][hh][dd], x1 = red[1][hh][dd], x2 = red[2][hh][dd], x3 = red[3][hh][dd];
    float4 s;
    s.x = (x0.x + x1.x) + (x2.x + x3.x);
    s.y = (x0.y + x1.y) + (x2.y + x3.y);
    s.z = (x0.z + x1.z) + (x2.z + x3.z);
    s.w = (x0.w + x1.w) + (x2.w + x3.w);
    ((float4*)(part + (((size_t)ch * B + b) * KVH + kvh) * 512))[t] = s;
  }
}

__global__ void k_reduce_ctx(const float* __restrict__ part, float* __restrict__ ctx) {
  int i = blockIdx.x * 256 + threadIdx.x;  // < B*D
  int b = i >> 12, r = i & 4095, h = r >> 7, d = r & 127;
  int kvh = h >> 2, hl = h & 3;
  float s = 0.f;
#pragma unroll
  for (int c = 0; c < NCH; c++)
    s += part[(((size_t)c * B + b) * KVH + kvh) * 512 + hl * 128 + d];
  ctx[i] = s;
}

// ----------------------------------------------- output projection (M=16)
__global__ void k_wo(const float* __restrict__ ctx, const float* __restrict__ Wo,
                     float* __restrict__ part) {
  int n = blockIdx.x * 256 + threadIdx.x;  // < 4096
  int k0 = blockIdx.y * (D / WSPLIT);
  float acc[B];
#pragma unroll
  for (int b = 0; b < B; b++) acc[b] = 0.f;
  const float* wp = Wo + (size_t)k0 * D + n;
#pragma unroll 8
  for (int k = 0; k < D / WSPLIT; k++) {
    float wv = wp[(size_t)k * D];
#pragma unroll
    for (int b = 0; b < B; b++) acc[b] = fmaf(ctx[b * D + k0 + k], wv, acc[b]);
  }
  float* p = part + (size_t)blockIdx.y * (B * D);
#pragma unroll
  for (int b = 0; b < B; b++) p[(size_t)b * D + n] = acc[b];
}

__global__ void k_reduce_out(const float* __restrict__ part, float* __restrict__ out) {
  int i = blockIdx.x * 256 + threadIdx.x;  // < B*D
  float s = 0.f;
#pragma unroll
  for (int c = 0; c < WSPLIT; c++) s += part[(size_t)c * B * D + i];
  out[i] = s;
}

// ----------------------------------------------------------------- launch
extern "C" void kernel_launch(void* const* d_in, const int* in_sizes, int n_in,
                              void* d_out, int out_size, void* d_ws, size_t ws_size,
                              hipStream_t stream) {
  const float* hs    = (const float*)d_in[0];
  const int*   steps = (const int*)d_in[2];
  const float* cosb  = (const float*)d_in[3];
  const float* sinb  = (const float*)d_in[4];
  const float* pk    = (const float*)d_in[5];
  const float* pvv   = (const float*)d_in[6];
  const float* Wq    = (const float*)d_in[7];
  const float* Wk    = (const float*)d_in[8];
  const float* Wv    = (const float*)d_in[9];
  const float* Wo    = (const float*)d_in[10];

  float* attn_out = (float*)d_out;
  float* newk = attn_out + (size_t)B * D;
  float* newv = newk + (size_t)B * KVH * S * HD;

  float* ws = (float*)d_ws;
  // Region A (lifetimes disjoint): proj partials (3.1M) -> scores/probs (2.1M)
  //                                -> Wo partials (2.1M)
  float* A        = ws;                               // 3,145,728 floats
  float* p_part   = A;
  float* p_scores = A;
  float* p_wopart = A;
  float* p_pvpart = A + 3145728;                      // 1,048,576
  float* p_qr     = p_pvpart + 1048576;               //    65,536
  float* p_nkrow  = p_qr + (size_t)B * D;             //    16,384
  float* p_nvrow  = p_nkrow + (size_t)B * KVH * HD;   //    16,384
  float* p_ctx    = p_nvrow + (size_t)B * KVH * HD;   //    65,536

  hipLaunchKernelGGL(k_proj, dim3(NQKV / 256, PSPLIT), dim3(256), 0, stream,
                     hs, Wq, Wk, Wv, p_part);
  hipLaunchKernelGGL(k_reduce_rope, dim3(B * NQKV / 256), dim3(256), 0, stream,
                     p_part, cosb, sinb, steps, p_qr, p_nkrow, p_nvrow);
  hipLaunchKernelGGL(k_fusedK, dim3(NCH, KVH, B), dim3(256), 0, stream,
                     pk, p_nkrow, p_qr, steps, newk, p_scores);
  hipLaunchKernelGGL(k_smax, dim3(B * H), dim3(256), 0, stream,
                     p_scores, steps);
  hipLaunchKernelGGL(k_fusedV, dim3(NCH, KVH, B), dim3(256), 0, stream,
                     pvv, p_nvrow, p_scores, steps, newv, p_pvpart);
  hipLaunchKernelGGL(k_reduce_ctx, dim3(B * D / 256), dim3(256), 0, stream,
                     p_pvpart, p_ctx);
  hipLaunchKernelGGL(k_wo, dim3(D / 256, WSPLIT), dim3(256), 0, stream,
                     p_ctx, Wo, p_wopart);
  hipLaunchKernelGGL(k_reduce_out, dim3(B * D / 256), dim3(256), 0, stream,
                     p_wopart, attn_out);
}